// Round 11
// baseline (258.848 us; speedup 1.0000x reference)
//
#include <hip/hip_runtime.h>
#include <math.h>

#define NPIX 6272       // B*H*W = 2*56*56
#define LVAL 3136       // H*W
#define CIN 192         // d_inner
#define NST 16          // d_state
#define HW 56
#define CHUNK 28
#define NCH 112         // LVAL / CHUNK

__device__ __forceinline__ float softplusf(float v) {
    return (v > 20.0f) ? v : log1pf(expf(v));
}

// K1: xz = x @ W_in ; 16 pixels/block, LDS-broadcast x, acc[16]/thread. (R10-exact)
__global__ __launch_bounds__(384) void k_inproj(
    const float* __restrict__ x, const float* __restrict__ W_in,
    float* __restrict__ xm, float* __restrict__ z)
{
    __shared__ __align__(16) float xs[96][20];
    const int p0 = blockIdx.x * 16;
    const int t = threadIdx.x;
    for (int e = t; e < 16 * 96; e += 384) {
        int p = e / 96, kk = e % 96;
        xs[kk][p] = x[p0 * 96 + e];
    }
    __syncthreads();
    float acc[16];
#pragma unroll
    for (int p = 0; p < 16; ++p) acc[p] = 0.f;
    for (int k = 0; k < 96; ++k) {
        float w = W_in[k * 384 + t];
        float4 x0 = *(const float4*)&xs[k][0];
        float4 x1 = *(const float4*)&xs[k][4];
        float4 x2 = *(const float4*)&xs[k][8];
        float4 x3 = *(const float4*)&xs[k][12];
        acc[0]  = fmaf(x0.x, w, acc[0]);  acc[1]  = fmaf(x0.y, w, acc[1]);
        acc[2]  = fmaf(x0.z, w, acc[2]);  acc[3]  = fmaf(x0.w, w, acc[3]);
        acc[4]  = fmaf(x1.x, w, acc[4]);  acc[5]  = fmaf(x1.y, w, acc[5]);
        acc[6]  = fmaf(x1.z, w, acc[6]);  acc[7]  = fmaf(x1.w, w, acc[7]);
        acc[8]  = fmaf(x2.x, w, acc[8]);  acc[9]  = fmaf(x2.y, w, acc[9]);
        acc[10] = fmaf(x2.z, w, acc[10]); acc[11] = fmaf(x2.w, w, acc[11]);
        acc[12] = fmaf(x3.x, w, acc[12]); acc[13] = fmaf(x3.y, w, acc[13]);
        acc[14] = fmaf(x3.z, w, acc[14]); acc[15] = fmaf(x3.w, w, acc[15]);
    }
#pragma unroll
    for (int p = 0; p < 16; ++p) {
        int pix = p0 + p;
        if (t < 192) xm[pix * CIN + t] = acc[p];
        else         z[pix * CIN + (t - 192)] = acc[p];
    }
}

// K2: depthwise 3x3 conv, pad 1 — float4 over channels. (R10-exact)
__global__ __launch_bounds__(256) void k_conv(
    const float* __restrict__ xm, const float* __restrict__ cw,
    const float* __restrict__ cb, float* __restrict__ xcv)
{
    int e = blockIdx.x * 256 + threadIdx.x;          // (pix, c-quad)
    if (e >= NPIX * (CIN / 4)) return;
    int cq = (e % (CIN / 4)) * 4;
    int pix = e / (CIN / 4);
    int w = pix % HW;
    int rest = pix / HW;
    int h = rest % HW;
    int b = rest / HW;
    float4 acc = *(const float4*)&cb[cq];
#pragma unroll
    for (int ky = 0; ky < 3; ++ky) {
        int hh = h + ky - 1;
        if (hh < 0 || hh >= HW) continue;
#pragma unroll
        for (int kx = 0; kx < 3; ++kx) {
            int ww = w + kx - 1;
            if (ww < 0 || ww >= HW) continue;
            float4 xv = *(const float4*)&xm[((b * HW + hh) * HW + ww) * CIN + cq];
            float4 wv = *(const float4*)&cw[(ky * 3 + kx) * CIN + cq];
            acc.x = fmaf(xv.x, wv.x, acc.x);
            acc.y = fmaf(xv.y, wv.y, acc.y);
            acc.z = fmaf(xv.z, wv.z, acc.z);
            acc.w = fmaf(xv.w, wv.w, acc.w);
        }
    }
    *(float4*)&xcv[pix * CIN + cq] = acc;
}

// K3: fused xproj + dt, K-SPLIT. (R10-exact)
__global__ __launch_bounds__(512) void k_xproj_dt(
    const float* __restrict__ xcv, const float* __restrict__ W_xproj,
    const float* __restrict__ W_dt, const float* __restrict__ b_dt,
    float* __restrict__ Bp, float* __restrict__ Cp, float2* __restrict__ dtx2)
{
    __shared__ __align__(16) float xs[192][28];
    __shared__ float part[2][24][40];
    __shared__ float dtr_lds[24][8];
    const int p0 = blockIdx.x * 24;
    const int t = threadIdx.x;
    for (int e = t; e < 24 * 192; e += 512) {
        int p = e / 192, kk = e % 192;
        int pix = p0 + p;
        xs[kk][p] = (pix < NPIX) ? xcv[pix * CIN + kk] : 0.f;
    }
    __syncthreads();
    const int th = t & 255;
    const int kh = t >> 8;               // 0..1 -> k range [kh*96, kh*96+96)
    const int j  = th % 40;
    const int pq = th / 40;              // 0..6; pq==6 idle
    if (pq < 6) {
        const int jc = (j < 38) ? j : 37;
        float a0 = 0.f, a1 = 0.f, a2 = 0.f, a3 = 0.f;
        const int k0 = kh * 96;
        for (int k = k0; k < k0 + 96; ++k) {
            float w = W_xproj[k * 38 + jc];
            float4 xv = *(const float4*)&xs[k][pq * 4];
            a0 = fmaf(xv.x, w, a0); a1 = fmaf(xv.y, w, a1);
            a2 = fmaf(xv.z, w, a2); a3 = fmaf(xv.w, w, a3);
        }
        part[kh][pq * 4 + 0][j] = a0;
        part[kh][pq * 4 + 1][j] = a1;
        part[kh][pq * 4 + 2][j] = a2;
        part[kh][pq * 4 + 3][j] = a3;
    }
    __syncthreads();
    if (kh == 0 && pq < 6 && j < 38) {
#pragma unroll
        for (int q = 0; q < 4; ++q) {
            int p = pq * 4 + q;
            float r = part[0][p][j] + part[1][p][j];
            int pix = p0 + p;
            if (j < 6) dtr_lds[p][j] = r;
            if (pix < NPIX) {
                if (j < 6)       ;   // dtr stays in LDS
                else if (j < 22) Bp[pix * NST + (j - 6)] = r;
                else             Cp[pix * NST + (j - 22)] = r;
            }
        }
    }
    __syncthreads();
    // Phase B: dt = softplus(dtr@W_dt + b_dt); pack with x from LDS.
    for (int e = t; e < 24 * 192; e += 512) {
        int p = e / 192, c = e % 192;
        int pix = p0 + p;
        if (pix >= NPIX) continue;
        float v = b_dt[c];
#pragma unroll
        for (int r = 0; r < 6; ++r)
            v = fmaf(dtr_lds[p][r], W_dt[r * CIN + c], v);
        dtx2[(size_t)pix * CIN + c] = make_float2(softplusf(v), xs[c][p]);
    }
}

// R11: direction-paired p1. Grid (112, 4, 2): y = pair*2 + b, z = ch-half.
// One block stages a chunk's dtx2/B into LDS ONCE and serves BOTH directions
// of a pair: pair0 (d0,d1) = forward + backward scans; pair1 (d2,d3) = one
// scan whose chunk-local result is IDENTICAL for both (d3 flips the slow
// axis only) -> summary written to both slots. Halves dtx2/Bp traffic and
// block count; per-direction arithmetic order unchanged (bit-identical).
__global__ __launch_bounds__(384) void k_scan_p1(
    const float2* __restrict__ dtx2, const float* __restrict__ Bp,
    const float* __restrict__ A_log,
    float* __restrict__ Sd, float* __restrict__ qbuf)
{
    __shared__ __align__(16) float Bs[CHUNK * NST];      // 1.8 KB
    __shared__ __align__(16) float2 dts[CHUNK][96];      // 21.5 KB
    const int k = blockIdx.x;
    const int pr = blockIdx.y >> 1, b = blockIdx.y & 1;
    const int ch = blockIdx.z;
    const int t = threadIdx.x;
    const int wv = t >> 6, lane = t & 63;
    const int cl = lane & 15, nh = lane >> 4;
    const int c = ch * 96 + wv * 16 + cl;
    const int cloc = wv * 16 + cl;
    const int n0 = nh * 4;
    const int i2 = k >> 1, jh = k & 1;
    // staged pixel for index jj (d0-forward order for pair0; d2 order for pair1)
    const int pbase = (pr == 0) ? (b * LVAL + i2 * HW + jh * 28)
                                : (b * LVAL + (jh * 28) * HW + i2);
    const int pstep = (pr == 0) ? 1 : HW;

    for (int e = t; e < CHUNK * NST; e += 384) {
        int jj = e >> 4, n = e & 15;
        Bs[e] = Bp[(pbase + jj * pstep) * NST + n];
    }
    for (int e = t; e < CHUNK * 96; e += 384) {
        int jj = e / 96, cc = e % 96;
        dts[jj][cc] = dtx2[(size_t)(pbase + jj * pstep) * CIN + ch * 96 + cc];
    }

    const float LOG2E = 1.4426950408889634f;
    float a2[4];
    {
        float4 v = *(const float4*)(A_log + c * NST + n0);
        a2[0] = -expf(v.x) * LOG2E;
        a2[1] = -expf(v.y) * LOG2E;
        a2[2] = -expf(v.z) * LOG2E;
        a2[3] = -expf(v.w) * LOG2E;
    }
    __syncthreads();

#define P1_STEP(JJ, H, SACC) do {                                        \
        float2 dv = dts[(JJ)][cloc];                                     \
        float dt_c = dv.x, x_c = dv.y;                                   \
        float dtx = dt_c * x_c;                                          \
        SACC += dt_c;                                                    \
        float4 t0 = *(const float4*)(Bs + (JJ) * NST + n0);              \
        float Bv[4] = {t0.x, t0.y, t0.z, t0.w};                          \
        _Pragma("unroll")                                                \
        for (int i = 0; i < 4; ++i) {                                    \
            float dA = exp2f(dt_c * a2[i]);                              \
            H[i] = fmaf(dA, H[i], dtx * Bv[i]);                          \
        }                                                                \
        (void)x_c;                                                       \
    } while (0)

#define P1_WRITE(KK, G, H, SACC) do {                                    \
        if (nh == 0)                                                     \
            Sd[(size_t)((KK) * 8 + (G)) * CIN + c] = (SACC);             \
        float4* qd = (float4*)(qbuf +                                    \
            ((size_t)((KK) * 8 + (G)) * CIN + c) * NST + n0);            \
        qd[0] = make_float4(H[0], H[1], H[2], H[3]);                     \
    } while (0)

    if (pr == 0) {
        // d0: forward
        float h[4] = {0.f, 0.f, 0.f, 0.f};
        float Sdt = 0.f;
        for (int jj = 0; jj < CHUNK; ++jj) P1_STEP(jj, h, Sdt);
        P1_WRITE(k, b, h, Sdt);
        // d1: backward over staged data (= d1's forward order)
        float hb[4] = {0.f, 0.f, 0.f, 0.f};
        float Sb = 0.f;
        for (int s = 0; s < CHUNK; ++s) { int jj = 27 - s; P1_STEP(jj, hb, Sb); }
        const int k1 = i2 * 2 + (1 - jh);
        P1_WRITE(k1, 2 + b, hb, Sb);
    } else {
        // d2 and d3 share the identical chunk-local scan
        float h[4] = {0.f, 0.f, 0.f, 0.f};
        float Sdt = 0.f;
        for (int jj = 0; jj < CHUNK; ++jj) P1_STEP(jj, h, Sdt);
        P1_WRITE(k, 4 + b, h, Sdt);
        const int k3 = (55 - i2) * 2 + jh;
        P1_WRITE(k3, 6 + b, h, Sdt);
    }
#undef P1_STEP
#undef P1_WRITE
}

// K4b: sequential chunk combine; P recomputed from Sdt + A_log. (R10-exact)
__global__ __launch_bounds__(256) void k_scan_fix(
    const float* __restrict__ Sd, const float* __restrict__ A_log,
    float* __restrict__ qbuf, int nch)
{
    const int g = blockIdx.y;
    const int lo = blockIdx.x * 256 + threadIdx.x;   // 0..3071 = c*16+n
    const int c = lo >> 4;
    const float LOG2E = 1.4426950408889634f;
    const float a2t = -expf(A_log[lo]) * LOG2E;
    const size_t stride = (size_t)8 * CIN * NST;
    const size_t sstride = (size_t)8 * CIN;
    size_t idx  = (size_t)g * CIN * NST + lo;
    size_t pidx = idx;
    size_t sidx = (size_t)g * CIN + c;
    float Sv[8], qr[8];
#pragma unroll
    for (int i = 0; i < 8; ++i) {
        Sv[i] = Sd[sidx]; qr[i] = qbuf[pidx];
        sidx += sstride; pidx += stride;
    }
    float h = 0.f;
    for (int k = 0; k < nch; k += 8) {
        float Sn[8], qn[8];
        if (k + 8 < nch) {
#pragma unroll
            for (int i = 0; i < 8; ++i) {
                Sn[i] = Sd[sidx + (size_t)i * sstride];
                qn[i] = qbuf[pidx + (size_t)i * stride];
            }
        } else {
#pragma unroll
            for (int i = 0; i < 8; ++i) { Sn[i] = 0.f; qn[i] = 0.f; }
        }
#pragma unroll
        for (int i = 0; i < 8; ++i) {
            qbuf[idx] = h;
            float P = exp2f(a2t * Sv[i]);
            h = fmaf(P, h, qr[i]);
            idx += stride;
        }
#pragma unroll
        for (int i = 0; i < 8; ++i) { Sv[i] = Sn[i]; qr[i] = qn[i]; }
        sidx += (size_t)8 * sstride;
        pidx += (size_t)8 * stride;
    }
}

// R11: direction-paired p2. Same staging as p1 (+Cs); pair0 runs forward(d0)
// + backward(d1) with their own carries; pair1 runs ONE loop with two
// h-states (d2,d3 carries) sharing the dA exp2s. y stored at each
// direction's own sequence position (Y4 is position-indexed per direction).
__global__ __launch_bounds__(384) void k_scan_p2(
    const float2* __restrict__ dtx2, const float* __restrict__ Bp,
    const float* __restrict__ Cp, const float* __restrict__ A_log,
    const float* __restrict__ D_skip,
    const float* __restrict__ qbuf, float* __restrict__ Y4)
{
    __shared__ __align__(16) float Bs[CHUNK * NST];      // 1.8 KB
    __shared__ __align__(16) float Cs[CHUNK * NST];      // 1.8 KB
    __shared__ __align__(16) float2 dts[CHUNK][96];      // 21.5 KB
    const int k = blockIdx.x;
    const int pr = blockIdx.y >> 1, b = blockIdx.y & 1;
    const int ch = blockIdx.z;
    const int t = threadIdx.x;
    const int wv = t >> 6, lane = t & 63;
    const int cl = lane & 15, nh = lane >> 4;
    const int c = ch * 96 + wv * 16 + cl;
    const int cloc = wv * 16 + cl;
    const int n0 = nh * 4;
    const int i2 = k >> 1, jh = k & 1;
    const int pbase = (pr == 0) ? (b * LVAL + i2 * HW + jh * 28)
                                : (b * LVAL + (jh * 28) * HW + i2);
    const int pstep = (pr == 0) ? 1 : HW;

    for (int e = t; e < CHUNK * NST; e += 384) {
        int jj = e >> 4, n = e & 15;
        int pa = (pbase + jj * pstep) * NST + n;
        Bs[e] = Bp[pa];
        Cs[e] = Cp[pa];
    }
    for (int e = t; e < CHUNK * 96; e += 384) {
        int jj = e / 96, cc = e % 96;
        dts[jj][cc] = dtx2[(size_t)(pbase + jj * pstep) * CIN + ch * 96 + cc];
    }

    const float LOG2E = 1.4426950408889634f;
    float a2[4];
    {
        float4 v = *(const float4*)(A_log + c * NST + n0);
        a2[0] = -expf(v.x) * LOG2E;
        a2[1] = -expf(v.y) * LOG2E;
        a2[2] = -expf(v.z) * LOG2E;
        a2[3] = -expf(v.w) * LOG2E;
    }
    const float Dc = D_skip[c];
    __syncthreads();

#define LOAD_H(H, KK, G) do {                                            \
        float4 vq = *(const float4*)(qbuf +                              \
            ((size_t)((KK) * 8 + (G)) * CIN + c) * NST + n0);            \
        H[0] = vq.x; H[1] = vq.y; H[2] = vq.z; H[3] = vq.w;              \
    } while (0)

#define P2_STEP(JJ, H, YO, POS) do {                                     \
        float2 dv = dts[(JJ)][cloc];                                     \
        float dt_c = dv.x, x_c = dv.y;                                   \
        float dtx = dt_c * x_c;                                          \
        float4 t0 = *(const float4*)(Bs + (JJ) * NST + n0);              \
        float4 u0 = *(const float4*)(Cs + (JJ) * NST + n0);              \
        float Bv[4] = {t0.x, t0.y, t0.z, t0.w};                          \
        float Cv[4] = {u0.x, u0.y, u0.z, u0.w};                          \
        float yc0 = 0.f, yc1 = 0.f;                                      \
        _Pragma("unroll")                                                \
        for (int i = 0; i < 4; i += 2) {                                 \
            float dA0 = exp2f(dt_c * a2[i]);                             \
            float dA1 = exp2f(dt_c * a2[i+1]);                           \
            H[i]   = fmaf(dA0, H[i],   dtx * Bv[i]);                     \
            H[i+1] = fmaf(dA1, H[i+1], dtx * Bv[i+1]);                   \
            yc0 = fmaf(H[i],   Cv[i],   yc0);                            \
            yc1 = fmaf(H[i+1], Cv[i+1], yc1);                            \
        }                                                                \
        float yc = yc0 + yc1;                                            \
        yc += __shfl_xor(yc, 16, 64);                                    \
        yc += __shfl_xor(yc, 32, 64);                                    \
        if (nh == 0)                                                     \
            (YO)[(POS) * CIN + c] = fmaf(Dc, x_c, yc);                   \
    } while (0)

    if (pr == 0) {
        // d0 forward
        float h[4];
        LOAD_H(h, k, b);
        float* yo0 = Y4 + ((size_t)0 * NPIX + (size_t)b * LVAL + (size_t)k * CHUNK) * CIN;
        for (int jj = 0; jj < CHUNK; ++jj) P2_STEP(jj, h, yo0, jj);
        // d1 backward (= d1's forward order); y at d1's sequence positions
        const int k1 = i2 * 2 + (1 - jh);
        float h1[4];
        LOAD_H(h1, k1, 2 + b);
        float* yo1 = Y4 + ((size_t)1 * NPIX + (size_t)b * LVAL + (size_t)k1 * CHUNK) * CIN;
        for (int s = 0; s < CHUNK; ++s) { int jj = 27 - s; P2_STEP(jj, h1, yo1, s); }
    } else {
        // d2 and d3: one loop, two h-states, shared dA
        const int k3 = (55 - i2) * 2 + jh;
        float h2[4], h3[4];
        LOAD_H(h2, k, 4 + b);
        LOAD_H(h3, k3, 6 + b);
        float* yo2 = Y4 + ((size_t)2 * NPIX + (size_t)b * LVAL + (size_t)k * CHUNK) * CIN;
        float* yo3 = Y4 + ((size_t)3 * NPIX + (size_t)b * LVAL + (size_t)k3 * CHUNK) * CIN;
        for (int jj = 0; jj < CHUNK; ++jj) {
            float2 dv = dts[jj][cloc];
            float dt_c = dv.x, x_c = dv.y;
            float dtx = dt_c * x_c;
            float4 t0 = *(const float4*)(Bs + jj * NST + n0);
            float4 u0 = *(const float4*)(Cs + jj * NST + n0);
            float Bv[4] = {t0.x, t0.y, t0.z, t0.w};
            float Cv[4] = {u0.x, u0.y, u0.z, u0.w};
            float y2a = 0.f, y2b = 0.f, y3a = 0.f, y3b = 0.f;
#pragma unroll
            for (int i = 0; i < 4; i += 2) {
                float dA0 = exp2f(dt_c * a2[i]);
                float dA1 = exp2f(dt_c * a2[i+1]);
                float dB0 = dtx * Bv[i], dB1 = dtx * Bv[i+1];
                h2[i]   = fmaf(dA0, h2[i],   dB0);
                h2[i+1] = fmaf(dA1, h2[i+1], dB1);
                h3[i]   = fmaf(dA0, h3[i],   dB0);
                h3[i+1] = fmaf(dA1, h3[i+1], dB1);
                y2a = fmaf(h2[i],   Cv[i],   y2a);
                y2b = fmaf(h2[i+1], Cv[i+1], y2b);
                y3a = fmaf(h3[i],   Cv[i],   y3a);
                y3b = fmaf(h3[i+1], Cv[i+1], y3b);
            }
            float y2 = y2a + y2b;
            float y3 = y3a + y3b;
            y2 += __shfl_xor(y2, 16, 64);
            y2 += __shfl_xor(y2, 32, 64);
            y3 += __shfl_xor(y3, 16, 64);
            y3 += __shfl_xor(y3, 32, 64);
            if (nh == 0) {
                yo2[jj * CIN + c] = fmaf(Dc, x_c, y2);
                yo3[jj * CIN + c] = fmaf(Dc, x_c, y3);
            }
        }
    }
#undef P2_STEP
#undef LOAD_H
}

// K5: fused gate + outproj. (R10-exact)
__global__ __launch_bounds__(384) void k_gateout(
    const float* __restrict__ Y4, const float* __restrict__ z,
    const float* __restrict__ W_out, float* __restrict__ out)
{
    __shared__ __align__(16) float xs[192][20];
    const int p0 = blockIdx.x * 16;
    const int t = threadIdx.x;
    const size_t NP = (size_t)NPIX * CIN;
    for (int e = t; e < 16 * 192; e += 384) {
        int p = e / 192, c = e % 192;
        size_t idx = (size_t)(p0 + p) * CIN + c;
        float s = Y4[idx] + Y4[idx + NP] + Y4[idx + 2 * NP] + Y4[idx + 3 * NP];
        float zz = z[idx];
        float sig = 1.f / (1.f + expf(-zz));
        xs[c][p] = zz * sig * s;
    }
    __syncthreads();
    const int j  = t % 96;
    const int ph = t / 96;          // 0..3 -> pixels ph*4 .. ph*4+3
    float acc[4] = {0.f, 0.f, 0.f, 0.f};
    for (int k = 0; k < 192; ++k) {
        float w = W_out[k * 96 + j];
        float4 xv = *(const float4*)&xs[k][ph * 4];
        acc[0] = fmaf(xv.x, w, acc[0]); acc[1] = fmaf(xv.y, w, acc[1]);
        acc[2] = fmaf(xv.z, w, acc[2]); acc[3] = fmaf(xv.w, w, acc[3]);
    }
#pragma unroll
    for (int p = 0; p < 4; ++p)
        out[(p0 + ph * 4 + p) * 96 + j] = acc[p];
}

extern "C" void kernel_launch(void* const* d_in, const int* in_sizes, int n_in,
                              void* d_out, int out_size, void* d_ws, size_t ws_size,
                              hipStream_t stream) {
    const float* x      = (const float*)d_in[0];
    const float* W_in   = (const float*)d_in[1];
    const float* conv_w = (const float*)d_in[2];
    const float* conv_b = (const float*)d_in[3];
    const float* W_xproj= (const float*)d_in[4];
    const float* W_dt   = (const float*)d_in[5];
    const float* b_dt   = (const float*)d_in[6];
    const float* A_log  = (const float*)d_in[7];
    const float* D_skip = (const float*)d_in[8];
    const float* W_out  = (const float*)d_in[9];
    float* out = (float*)d_out;

    float* ws   = (float*)d_ws;
    float* xm   = ws;                        // [NPIX*CIN]
    float* z    = xm  + NPIX * CIN;          // [NPIX*CIN]
    float* xcv  = z   + NPIX * CIN;          // [NPIX*CIN]
    float2* dtx2= (float2*)(xcv + NPIX * CIN); // [NPIX*CIN] float2
    float* Bp   = (float*)(dtx2 + (size_t)NPIX * CIN); // [NPIX*NST]
    float* Cp   = Bp  + NPIX * NST;          // [NPIX*NST]
    float* Y4   = Cp  + NPIX * NST;          // [4*NPIX*CIN] (d-major slabs)
    float* Sd   = Y4  + (size_t)4 * NPIX * CIN;          // [NCH*8*CIN]
    float* qbuf = Sd  + (size_t)NCH * 8 * CIN;           // [NCH*8*CIN*NST]

    k_inproj  <<<NPIX / 16, 384, 0, stream>>>(x, W_in, xm, z);
    k_conv    <<<(NPIX * (CIN / 4)) / 256, 256, 0, stream>>>(xm, conv_w, conv_b, xcv);
    k_xproj_dt<<<(NPIX + 23) / 24, 512, 0, stream>>>(xcv, W_xproj, W_dt, b_dt, Bp, Cp, dtx2);
    k_scan_p1 <<<dim3(NCH, 4, 2), 384, 0, stream>>>(dtx2, Bp, A_log, Sd, qbuf);
    k_scan_fix<<<dim3(12, 8), 256, 0, stream>>>(Sd, A_log, qbuf, NCH);
    k_scan_p2 <<<dim3(NCH, 4, 2), 384, 0, stream>>>(dtx2, Bp, Cp, A_log, D_skip, qbuf, Y4);
    k_gateout <<<NPIX / 16, 384, 0, stream>>>(Y4, z, W_out, out);
}

// Round 12
// 194.159 us; speedup vs baseline: 1.3332x; 1.3332x over previous
//
#include <hip/hip_runtime.h>
#include <math.h>

#define NPIX 6272       // B*H*W = 2*56*56
#define LVAL 3136       // H*W
#define CIN 192         // d_inner
#define NST 16          // d_state
#define HW 56
#define CHUNK 28
#define NCH 112         // LVAL / CHUNK

__device__ __forceinline__ float softplusf(float v) {
    return (v > 20.0f) ? v : log1pf(expf(v));
}

// direction geometry: pixel(l) = off + i*si + j*sj, l = i*56 + j
__device__ __forceinline__ void dir_geom(int d, int b, int& si, int& sj, int& off) {
    if (d == 0)      { si = HW;  sj = 1;   off = b * LVAL; }
    else if (d == 1) { si = HW;  sj = -1;  off = b * LVAL + (HW - 1); }
    else if (d == 2) { si = 1;   sj = HW;  off = b * LVAL; }
    else             { si = -1;  sj = HW;  off = b * LVAL + (HW - 1); }
}

// K1: xz = x @ W_in ; 16 pixels/block, LDS-broadcast x, acc[16]/thread.
__global__ __launch_bounds__(384) void k_inproj(
    const float* __restrict__ x, const float* __restrict__ W_in,
    float* __restrict__ xm, float* __restrict__ z)
{
    __shared__ __align__(16) float xs[96][20];
    const int p0 = blockIdx.x * 16;
    const int t = threadIdx.x;
    for (int e = t; e < 16 * 96; e += 384) {
        int p = e / 96, kk = e % 96;
        xs[kk][p] = x[p0 * 96 + e];
    }
    __syncthreads();
    float acc[16];
#pragma unroll
    for (int p = 0; p < 16; ++p) acc[p] = 0.f;
    for (int k = 0; k < 96; ++k) {
        float w = W_in[k * 384 + t];
        float4 x0 = *(const float4*)&xs[k][0];
        float4 x1 = *(const float4*)&xs[k][4];
        float4 x2 = *(const float4*)&xs[k][8];
        float4 x3 = *(const float4*)&xs[k][12];
        acc[0]  = fmaf(x0.x, w, acc[0]);  acc[1]  = fmaf(x0.y, w, acc[1]);
        acc[2]  = fmaf(x0.z, w, acc[2]);  acc[3]  = fmaf(x0.w, w, acc[3]);
        acc[4]  = fmaf(x1.x, w, acc[4]);  acc[5]  = fmaf(x1.y, w, acc[5]);
        acc[6]  = fmaf(x1.z, w, acc[6]);  acc[7]  = fmaf(x1.w, w, acc[7]);
        acc[8]  = fmaf(x2.x, w, acc[8]);  acc[9]  = fmaf(x2.y, w, acc[9]);
        acc[10] = fmaf(x2.z, w, acc[10]); acc[11] = fmaf(x2.w, w, acc[11]);
        acc[12] = fmaf(x3.x, w, acc[12]); acc[13] = fmaf(x3.y, w, acc[13]);
        acc[14] = fmaf(x3.z, w, acc[14]); acc[15] = fmaf(x3.w, w, acc[15]);
    }
#pragma unroll
    for (int p = 0; p < 16; ++p) {
        int pix = p0 + p;
        if (t < 192) xm[pix * CIN + t] = acc[p];
        else         z[pix * CIN + (t - 192)] = acc[p];
    }
}

// K2: depthwise 3x3 conv, pad 1 — float4 over channels (4 ch/thread).
__global__ __launch_bounds__(256) void k_conv(
    const float* __restrict__ xm, const float* __restrict__ cw,
    const float* __restrict__ cb, float* __restrict__ xcv)
{
    int e = blockIdx.x * 256 + threadIdx.x;          // (pix, c-quad)
    if (e >= NPIX * (CIN / 4)) return;
    int cq = (e % (CIN / 4)) * 4;
    int pix = e / (CIN / 4);
    int w = pix % HW;
    int rest = pix / HW;
    int h = rest % HW;
    int b = rest / HW;
    float4 acc = *(const float4*)&cb[cq];
#pragma unroll
    for (int ky = 0; ky < 3; ++ky) {
        int hh = h + ky - 1;
        if (hh < 0 || hh >= HW) continue;
#pragma unroll
        for (int kx = 0; kx < 3; ++kx) {
            int ww = w + kx - 1;
            if (ww < 0 || ww >= HW) continue;
            float4 xv = *(const float4*)&xm[((b * HW + hh) * HW + ww) * CIN + cq];
            float4 wv = *(const float4*)&cw[(ky * 3 + kx) * CIN + cq];
            acc.x = fmaf(xv.x, wv.x, acc.x);
            acc.y = fmaf(xv.y, wv.y, acc.y);
            acc.z = fmaf(xv.z, wv.z, acc.z);
            acc.w = fmaf(xv.w, wv.w, acc.w);
        }
    }
    *(float4*)&xcv[pix * CIN + cq] = acc;
}

// K3: fused xproj + dt, K-SPLIT. 24 pixels/block, 512 threads = 2 k-halves
// of 96 iters each; partials combined in LDS. Phase B writes packed
// float2(dt, x) so the scan does ONE dwordx2 load per step.
__global__ __launch_bounds__(512) void k_xproj_dt(
    const float* __restrict__ xcv, const float* __restrict__ W_xproj,
    const float* __restrict__ W_dt, const float* __restrict__ b_dt,
    float* __restrict__ Bp, float* __restrict__ Cp, float2* __restrict__ dtx2)
{
    __shared__ __align__(16) float xs[192][28];
    __shared__ float part[2][24][40];
    __shared__ float dtr_lds[24][8];
    const int p0 = blockIdx.x * 24;
    const int t = threadIdx.x;
    for (int e = t; e < 24 * 192; e += 512) {
        int p = e / 192, kk = e % 192;
        int pix = p0 + p;
        xs[kk][p] = (pix < NPIX) ? xcv[pix * CIN + kk] : 0.f;
    }
    __syncthreads();
    const int th = t & 255;
    const int kh = t >> 8;               // 0..1 -> k range [kh*96, kh*96+96)
    const int j  = th % 40;
    const int pq = th / 40;              // 0..6; pq==6 idle
    if (pq < 6) {
        const int jc = (j < 38) ? j : 37;
        float a0 = 0.f, a1 = 0.f, a2 = 0.f, a3 = 0.f;
        const int k0 = kh * 96;
        for (int k = k0; k < k0 + 96; ++k) {
            float w = W_xproj[k * 38 + jc];
            float4 xv = *(const float4*)&xs[k][pq * 4];
            a0 = fmaf(xv.x, w, a0); a1 = fmaf(xv.y, w, a1);
            a2 = fmaf(xv.z, w, a2); a3 = fmaf(xv.w, w, a3);
        }
        part[kh][pq * 4 + 0][j] = a0;
        part[kh][pq * 4 + 1][j] = a1;
        part[kh][pq * 4 + 2][j] = a2;
        part[kh][pq * 4 + 3][j] = a3;
    }
    __syncthreads();
    if (kh == 0 && pq < 6 && j < 38) {
#pragma unroll
        for (int q = 0; q < 4; ++q) {
            int p = pq * 4 + q;
            float r = part[0][p][j] + part[1][p][j];
            int pix = p0 + p;
            if (j < 6) dtr_lds[p][j] = r;
            if (pix < NPIX) {
                if (j < 6)       ;   // dtr stays in LDS
                else if (j < 22) Bp[pix * NST + (j - 6)] = r;
                else             Cp[pix * NST + (j - 22)] = r;
            }
        }
    }
    __syncthreads();
    // Phase B: dt = softplus(dtr@W_dt + b_dt); pack with x from LDS.
    for (int e = t; e < 24 * 192; e += 512) {
        int p = e / 192, c = e % 192;
        int pix = p0 + p;
        if (pix >= NPIX) continue;
        float v = b_dt[c];
#pragma unroll
        for (int r = 0; r < 6; ++r)
            v = fmaf(dtr_lds[p][r], W_dt[r * CIN + c], v);
        dtx2[(size_t)pix * CIN + c] = make_float2(softplusf(v), xs[c][p]);
    }
}

// K4a pass1 — R2 geometry (4-way n-split, grid (112,8,2)).
// Sdt-opt: store Sdt (scalar per channel) instead of P (float4);
// k_scan_fix recomputes P = exp2(a2*Sdt) with the identical formula ->
// bit-identical results, ~21 MB less traffic. (R10-verified: 194.1us)
__global__ __launch_bounds__(384) void k_scan_p1(
    const float2* __restrict__ dtx2, const float* __restrict__ Bp,
    const float* __restrict__ A_log,
    float* __restrict__ Sd, float* __restrict__ qbuf)
{
    constexpr int CPR = HW / CHUNK;
    __shared__ __align__(16) float Bs[CHUNK * NST];
    const int g = blockIdx.y;
    const int k = blockIdx.x;
    const int ch = blockIdx.z;           // channel half: [ch*96, ch*96+96)
    const int t = threadIdx.x;
    const int wv = t >> 6;
    const int lane = t & 63;
    const int cl = lane & 15, nh = lane >> 4;   // 16 channels x 4 n-groups
    const int c = ch * 96 + wv * 16 + cl;
    const int n0 = nh * 4;
    const int d = g >> 1, b = g & 1;
    int si, sj, off;
    dir_geom(d, b, si, sj, off);
    const int base = off + (k / CPR) * si + ((k % CPR) * CHUNK) * sj;

    for (int e = t; e < CHUNK * NST; e += 384) {
        int jj = e >> 4, n = e & 15;
        Bs[e] = Bp[(base + jj * sj) * NST + n];
    }

    const float LOG2E = 1.4426950408889634f;
    float a2[4];
    {
        float4 v = *(const float4*)(A_log + c * NST + n0);
        a2[0] = -expf(v.x) * LOG2E;
        a2[1] = -expf(v.y) * LOG2E;
        a2[2] = -expf(v.z) * LOG2E;
        a2[3] = -expf(v.w) * LOG2E;
    }
    __syncthreads();

    float h[4];
#pragma unroll
    for (int i = 0; i < 4; ++i) h[i] = 0.f;
    float Sdt = 0.f;

    const float2* dp = dtx2 + (size_t)base * CIN + c;
    const ptrdiff_t dstep = (ptrdiff_t)sj * CIN;

#define P1_STEP(DVV, JJ) do {                                            \
        float dt_c = (DVV).x, x_c = (DVV).y;                             \
        float dtx = dt_c * x_c;                                          \
        Sdt += dt_c;                                                     \
        float4 t0 = *(const float4*)(Bs + (JJ) * NST + n0);              \
        float Bv[4] = {t0.x, t0.y, t0.z, t0.w};                          \
        _Pragma("unroll")                                                \
        for (int i = 0; i < 4; ++i) {                                    \
            float dA = exp2f(dt_c * a2[i]);                              \
            h[i] = fmaf(dA, h[i], dtx * Bv[i]);                          \
        }                                                                \
    } while (0)

    float2 v0 = dp[0];
    float2 v1 = dp[dstep];
    float2 v2 = dp[2 * dstep];
    float2 v3 = dp[3 * dstep];
    for (int jj = 0; jj < CHUNK; jj += 4) {
        const int j4 = (jj + 4 < CHUNK) ? jj + 4 : CHUNK - 4;
        float2 nv0 = dp[(ptrdiff_t)(j4 + 0) * dstep];
        float2 nv1 = dp[(ptrdiff_t)(j4 + 1) * dstep];
        float2 nv2 = dp[(ptrdiff_t)(j4 + 2) * dstep];
        float2 nv3 = dp[(ptrdiff_t)(j4 + 3) * dstep];
        P1_STEP(v0, jj + 0);
        P1_STEP(v1, jj + 1);
        P1_STEP(v2, jj + 2);
        P1_STEP(v3, jj + 3);
        v0 = nv0; v1 = nv1; v2 = nv2; v3 = nv3;
    }
#undef P1_STEP

    if (nh == 0)
        Sd[(size_t)(k * 8 + g) * CIN + c] = Sdt;   // shared across n-groups
    float4* qd = (float4*)(qbuf + ((size_t)(k * 8 + g) * CIN + c) * NST + n0);
    qd[0] = make_float4(h[0], h[1], h[2], h[3]);
}

// K4b: sequential chunk combine. P recomputed from Sdt + A_log inline
// (identical -expf(A_log)*LOG2E formula as p1 -> bit-identical P).
__global__ __launch_bounds__(256) void k_scan_fix(
    const float* __restrict__ Sd, const float* __restrict__ A_log,
    float* __restrict__ qbuf, int nch)
{
    const int g = blockIdx.y;
    const int lo = blockIdx.x * 256 + threadIdx.x;   // 0..3071 = c*16+n
    const int c = lo >> 4;
    const float LOG2E = 1.4426950408889634f;
    const float a2t = -expf(A_log[lo]) * LOG2E;
    const size_t stride = (size_t)8 * CIN * NST;
    const size_t sstride = (size_t)8 * CIN;
    size_t idx  = (size_t)g * CIN * NST + lo;
    size_t pidx = idx;
    size_t sidx = (size_t)g * CIN + c;
    float Sv[8], qr[8];
#pragma unroll
    for (int i = 0; i < 8; ++i) {
        Sv[i] = Sd[sidx]; qr[i] = qbuf[pidx];
        sidx += sstride; pidx += stride;
    }
    float h = 0.f;
    for (int k = 0; k < nch; k += 8) {
        float Sn[8], qn[8];
        if (k + 8 < nch) {
#pragma unroll
            for (int i = 0; i < 8; ++i) {
                Sn[i] = Sd[sidx + (size_t)i * sstride];
                qn[i] = qbuf[pidx + (size_t)i * stride];
            }
        } else {
#pragma unroll
            for (int i = 0; i < 8; ++i) { Sn[i] = 0.f; qn[i] = 0.f; }
        }
#pragma unroll
        for (int i = 0; i < 8; ++i) {
            qbuf[idx] = h;
            float P = exp2f(a2t * Sv[i]);
            h = fmaf(P, h, qr[i]);
            idx += stride;
        }
#pragma unroll
        for (int i = 0; i < 8; ++i) { Sv[i] = Sn[i]; qr[i] = qn[i]; }
        sidx += (size_t)8 * sstride;
        pidx += (size_t)8 * stride;
    }
}

// K4c pass2 — R2-exact: 4-way n-split; y via shfl_xor(16)+shfl_xor(32).
__global__ __launch_bounds__(384) void k_scan_p2(
    const float2* __restrict__ dtx2, const float* __restrict__ Bp,
    const float* __restrict__ Cp, const float* __restrict__ A_log,
    const float* __restrict__ D_skip,
    const float* __restrict__ qbuf, float* __restrict__ Y4)
{
    constexpr int CPR = HW / CHUNK;
    __shared__ __align__(16) float Bs[CHUNK * NST];
    __shared__ __align__(16) float Cs[CHUNK * NST];
    const int g = blockIdx.y;
    const int k = blockIdx.x;
    const int ch = blockIdx.z;
    const int t = threadIdx.x;
    const int wv = t >> 6;
    const int lane = t & 63;
    const int cl = lane & 15, nh = lane >> 4;
    const int c = ch * 96 + wv * 16 + cl;
    const int n0 = nh * 4;
    const int d = g >> 1, b = g & 1;
    int si, sj, off;
    dir_geom(d, b, si, sj, off);
    const int base = off + (k / CPR) * si + ((k % CPR) * CHUNK) * sj;

    for (int e = t; e < CHUNK * NST; e += 384) {
        int jj = e >> 4, n = e & 15;
        int pa = (base + jj * sj) * NST + n;
        Bs[e] = Bp[pa];
        Cs[e] = Cp[pa];
    }

    const float LOG2E = 1.4426950408889634f;
    float a2[4];
    {
        float4 v = *(const float4*)(A_log + c * NST + n0);
        a2[0] = -expf(v.x) * LOG2E;
        a2[1] = -expf(v.y) * LOG2E;
        a2[2] = -expf(v.z) * LOG2E;
        a2[3] = -expf(v.w) * LOG2E;
    }
    const float Dc = D_skip[c];

    float h[4];
    {
        float4 v0q = *(const float4*)(qbuf + ((size_t)(k * 8 + g) * CIN + c) * NST + n0);
        h[0]=v0q.x; h[1]=v0q.y; h[2]=v0q.z; h[3]=v0q.w;
    }
    __syncthreads();

    float* yo = Y4 + ((size_t)d * NPIX + (size_t)b * LVAL + (size_t)k * CHUNK) * CIN;

    const float2* dp = dtx2 + (size_t)base * CIN + c;
    const ptrdiff_t dstep = (ptrdiff_t)sj * CIN;

#define P2_STEP(DVV, JJ) do {                                            \
        float dt_c = (DVV).x, x_c = (DVV).y;                             \
        float dtx = dt_c * x_c;                                          \
        float4 t0 = *(const float4*)(Bs + (JJ) * NST + n0);              \
        float4 u0 = *(const float4*)(Cs + (JJ) * NST + n0);              \
        float Bv[4] = {t0.x, t0.y, t0.z, t0.w};                          \
        float Cv[4] = {u0.x, u0.y, u0.z, u0.w};                          \
        float yc0 = 0.f, yc1 = 0.f;                                      \
        _Pragma("unroll")                                                \
        for (int i = 0; i < 4; i += 2) {                                 \
            float dA0 = exp2f(dt_c * a2[i]);                             \
            float dA1 = exp2f(dt_c * a2[i+1]);                           \
            h[i]   = fmaf(dA0, h[i],   dtx * Bv[i]);                     \
            h[i+1] = fmaf(dA1, h[i+1], dtx * Bv[i+1]);                   \
            yc0 = fmaf(h[i],   Cv[i],   yc0);                            \
            yc1 = fmaf(h[i+1], Cv[i+1], yc1);                            \
        }                                                                \
        float yc = yc0 + yc1;                                            \
        yc += __shfl_xor(yc, 16, 64);                                    \
        yc += __shfl_xor(yc, 32, 64);                                    \
        if (nh == 0)                                                     \
            yo[(JJ) * CIN + c] = fmaf(Dc, x_c, yc);                      \
    } while (0)

    float2 v0 = dp[0];
    float2 v1 = dp[dstep];
    float2 v2 = dp[2 * dstep];
    float2 v3 = dp[3 * dstep];
    for (int jj = 0; jj < CHUNK; jj += 4) {
        const int j4 = (jj + 4 < CHUNK) ? jj + 4 : CHUNK - 4;
        float2 nv0 = dp[(ptrdiff_t)(j4 + 0) * dstep];
        float2 nv1 = dp[(ptrdiff_t)(j4 + 1) * dstep];
        float2 nv2 = dp[(ptrdiff_t)(j4 + 2) * dstep];
        float2 nv3 = dp[(ptrdiff_t)(j4 + 3) * dstep];
        P2_STEP(v0, jj + 0);
        P2_STEP(v1, jj + 1);
        P2_STEP(v2, jj + 2);
        P2_STEP(v3, jj + 3);
        v0 = nv0; v1 = nv1; v2 = nv2; v3 = nv3;
    }
#undef P2_STEP
}

// K5: fused gate + outproj. 16 pixels/block, 384 threads, acc[4]/thread.
__global__ __launch_bounds__(384) void k_gateout(
    const float* __restrict__ Y4, const float* __restrict__ z,
    const float* __restrict__ W_out, float* __restrict__ out)
{
    __shared__ __align__(16) float xs[192][20];
    const int p0 = blockIdx.x * 16;
    const int t = threadIdx.x;
    const size_t NP = (size_t)NPIX * CIN;
    for (int e = t; e < 16 * 192; e += 384) {
        int p = e / 192, c = e % 192;
        size_t idx = (size_t)(p0 + p) * CIN + c;
        float s = Y4[idx] + Y4[idx + NP] + Y4[idx + 2 * NP] + Y4[idx + 3 * NP];
        float zz = z[idx];
        float sig = 1.f / (1.f + expf(-zz));
        xs[c][p] = zz * sig * s;
    }
    __syncthreads();
    const int j  = t % 96;
    const int ph = t / 96;          // 0..3 -> pixels ph*4 .. ph*4+3
    float acc[4] = {0.f, 0.f, 0.f, 0.f};
    for (int k = 0; k < 192; ++k) {
        float w = W_out[k * 96 + j];
        float4 xv = *(const float4*)&xs[k][ph * 4];
        acc[0] = fmaf(xv.x, w, acc[0]); acc[1] = fmaf(xv.y, w, acc[1]);
        acc[2] = fmaf(xv.z, w, acc[2]); acc[3] = fmaf(xv.w, w, acc[3]);
    }
#pragma unroll
    for (int p = 0; p < 4; ++p)
        out[(p0 + ph * 4 + p) * 96 + j] = acc[p];
}

extern "C" void kernel_launch(void* const* d_in, const int* in_sizes, int n_in,
                              void* d_out, int out_size, void* d_ws, size_t ws_size,
                              hipStream_t stream) {
    const float* x      = (const float*)d_in[0];
    const float* W_in   = (const float*)d_in[1];
    const float* conv_w = (const float*)d_in[2];
    const float* conv_b = (const float*)d_in[3];
    const float* W_xproj= (const float*)d_in[4];
    const float* W_dt   = (const float*)d_in[5];
    const float* b_dt   = (const float*)d_in[6];
    const float* A_log  = (const float*)d_in[7];
    const float* D_skip = (const float*)d_in[8];
    const float* W_out  = (const float*)d_in[9];
    float* out = (float*)d_out;

    float* ws   = (float*)d_ws;
    float* xm   = ws;                        // [NPIX*CIN]
    float* z    = xm  + NPIX * CIN;          // [NPIX*CIN]
    float* xcv  = z   + NPIX * CIN;          // [NPIX*CIN]
    float2* dtx2= (float2*)(xcv + NPIX * CIN); // [NPIX*CIN] float2
    float* Bp   = (float*)(dtx2 + (size_t)NPIX * CIN); // [NPIX*NST]
    float* Cp   = Bp  + NPIX * NST;          // [NPIX*NST]
    float* Y4   = Cp  + NPIX * NST;          // [4*NPIX*CIN] (d-major slabs)
    float* Sd   = Y4  + (size_t)4 * NPIX * CIN;          // [NCH*8*CIN]
    float* qbuf = Sd  + (size_t)NCH * 8 * CIN;           // [NCH*8*CIN*NST]
    // total ~14.2M floats = 57 MB (ws is 268 MB)

    k_inproj  <<<NPIX / 16, 384, 0, stream>>>(x, W_in, xm, z);
    k_conv    <<<(NPIX * (CIN / 4)) / 256, 256, 0, stream>>>(xm, conv_w, conv_b, xcv);
    k_xproj_dt<<<(NPIX + 23) / 24, 512, 0, stream>>>(xcv, W_xproj, W_dt, b_dt, Bp, Cp, dtx2);
    k_scan_p1 <<<dim3(NCH, 8, 2), 384, 0, stream>>>(dtx2, Bp, A_log, Sd, qbuf);
    k_scan_fix<<<dim3(12, 8), 256, 0, stream>>>(Sd, A_log, qbuf, NCH);
    k_scan_p2 <<<dim3(NCH, 8, 2), 384, 0, stream>>>(dtx2, Bp, Cp, A_log, D_skip, qbuf, Y4);
    k_gateout <<<NPIX / 16, 384, 0, stream>>>(Y4, z, W_out, out);
}